// Round 3
// baseline (111.081 us; speedup 1.0000x reference)
//
#include <hip/hip_runtime.h>

#define B_DIM 1024
#define C_DIM 256
#define EPS 1e-8f
#define LAMBDA_LPR 0.1f

// ws layout (16 bytes): acc[0]=bce sum (f32), acc[1]=pair-log sum (f32),
//                       acc_u[2]=pair count (u32), acc_u[3]=blocks-done counter (u32)

__global__ __launch_bounds__(256) void spa_lpr_kernel(const float* __restrict__ logits,
                                                      const float* __restrict__ targets,
                                                      float* __restrict__ acc,
                                                      float* __restrict__ out) {
    __shared__ float Eneg_s[C_DIM];      // compacted e^{p} of negatives, zero-padded to mult of 32
    __shared__ unsigned int wcnt[4];
    __shared__ float r0[4], r1[4];

    const int row  = blockIdx.x;
    const int j    = threadIdx.x;
    const int lane = j & 63;
    const int wave = j >> 6;

    const float x = logits[row * C_DIM + j];
    const float t = targets[row * C_DIM + j];
    const float p = 1.0f / (1.0f + __expf(-x));
    const float E = __expf(p);           // e^{prob}, in (1, e)

    // elementwise BCE (SPA) term
    const float bce = -t * __logf(p + EPS) - (1.0f - t) * __logf(1.0f - p + EPS);

    // ---- compact negatives (t == 0) into Eneg_s via ballot + prefix ----
    const bool isneg = (t == 0.0f);
    const unsigned long long m = __ballot(isneg);
    const unsigned int rank = (unsigned int)__popcll(m & ((1ull << lane) - 1ull));
    if (lane == 0) wcnt[wave] = (unsigned int)__popcll(m);
    __syncthreads();
    unsigned int off = 0;
    #pragma unroll
    for (int w = 0; w < 4; ++w) if (w < wave) off += wcnt[w];
    const unsigned int nneg = wcnt[0] + wcnt[1] + wcnt[2] + wcnt[3];
    if (isneg) Eneg_s[off + rank] = E;
    const unsigned int L = (nneg + 31u) & ~31u;   // <= 256
    if ((unsigned int)j >= nneg && (unsigned int)j < L) Eneg_s[j] = 0.0f;  // pad: log(E+0)=p, corrected below
    __syncthreads();

    // ---- pairwise term: S = sum_k log(E + Eneg[k]) via grouped products ----
    // log1p(exp(p_n - p_p)) = log(E_p + E_n) - p_p ; zero-pad contributes exactly p_p each.
    float S = 0.0f;
    const float Ep = E;
    for (unsigned int k0 = 0; k0 < L; k0 += 32) {
        float pr0 = 1.0f, pr1 = 1.0f, pr2 = 1.0f, pr3 = 1.0f;
        #pragma unroll
        for (int kk = 0; kk < 32; kk += 4) {
            const float4 e = *reinterpret_cast<const float4*>(&Eneg_s[k0 + kk]);
            pr0 *= (Ep + e.x);
            pr1 *= (Ep + e.y);
            pr2 *= (Ep + e.z);
            pr3 *= (Ep + e.w);
        }
        S += __logf((pr0 * pr1) * (pr2 * pr3));   // product <= 5.34^32 ~ 2^77, fp32-safe
    }
    float pair = t * (S - p * (float)L);          // t in {0,1} masks non-positive rows

    // ---- block reduction of bce & pair ----
    float b = bce;
    #pragma unroll
    for (int o = 32; o > 0; o >>= 1) {
        b    += __shfl_down(b, o);
        pair += __shfl_down(pair, o);
    }
    if (lane == 0) { r0[wave] = b; r1[wave] = pair; }
    __syncthreads();

    if (j == 0) {
        const float bs = r0[0] + r0[1] + r0[2] + r0[3];
        const float ps = r1[0] + r1[1] + r1[2] + r1[3];
        atomicAdd(&acc[0], bs);
        atomicAdd(&acc[1], ps);
        const unsigned int npos = (unsigned int)C_DIM - nneg;
        atomicAdd((unsigned int*)&acc[2], npos * nneg);
        __threadfence();
        const unsigned int done = atomicAdd((unsigned int*)&acc[3], 1u);
        if (done == (unsigned int)(B_DIM - 1)) {
            // last block finalizes; atomic RMW reads guarantee device-scope visibility
            const float bsum = atomicAdd(&acc[0], 0.0f);
            const float psum = atomicAdd(&acc[1], 0.0f);
            const unsigned int cnt = atomicAdd((unsigned int*)&acc[2], 0u);
            out[0] = bsum / (float)(B_DIM * C_DIM) + LAMBDA_LPR * (psum / ((float)cnt + EPS));
        }
    }
}

extern "C" void kernel_launch(void* const* d_in, const int* in_sizes, int n_in,
                              void* d_out, int out_size, void* d_ws, size_t ws_size,
                              hipStream_t stream) {
    const float* logits  = (const float*)d_in[0];
    const float* targets = (const float*)d_in[1];
    float* out = (float*)d_out;
    float* acc = (float*)d_ws;

    hipMemsetAsync(acc, 0, 4 * sizeof(float), stream);
    spa_lpr_kernel<<<B_DIM, 256, 0, stream>>>(logits, targets, acc, out);
}

// Round 4
// 60.687 us; speedup vs baseline: 1.8304x; 1.8304x over previous
//
#include <hip/hip_runtime.h>

#define B_DIM 1024
#define C_DIM 256
#define EPS 1e-8f
#define LAMBDA_LPR 0.1f

// ws layout: float4 part[B_DIM] (16 KB): {bce_sum, pair_sum, (float)(npos*nneg), 0}
// No atomics anywhere: kernel1 = plain per-row stores, kernel2 = single-block reduce.

__global__ __launch_bounds__(256) void spa_lpr_partial(const float* __restrict__ logits,
                                                       const float* __restrict__ targets,
                                                       float4* __restrict__ part) {
    __shared__ float Eneg_s[C_DIM];      // compacted e^{p} of negatives, zero-padded to mult of 32
    __shared__ unsigned int wcnt[4];
    __shared__ float r0[4], r1[4];

    const int row  = blockIdx.x;
    const int j    = threadIdx.x;
    const int lane = j & 63;
    const int wave = j >> 6;

    const float x = logits[row * C_DIM + j];
    const float t = targets[row * C_DIM + j];
    const float p = 1.0f / (1.0f + __expf(-x));
    const float E = __expf(p);           // e^{prob}, in (1, e)

    // elementwise BCE (SPA) term
    const float bce = -t * __logf(p + EPS) - (1.0f - t) * __logf(1.0f - p + EPS);

    // ---- compact negatives (t == 0) into Eneg_s via ballot + prefix ----
    const bool isneg = (t == 0.0f);
    const unsigned long long m = __ballot(isneg);
    const unsigned int rank = (unsigned int)__popcll(m & ((1ull << lane) - 1ull));
    if (lane == 0) wcnt[wave] = (unsigned int)__popcll(m);
    __syncthreads();
    unsigned int off = 0;
    #pragma unroll
    for (int w = 0; w < 4; ++w) if (w < wave) off += wcnt[w];
    const unsigned int nneg = wcnt[0] + wcnt[1] + wcnt[2] + wcnt[3];
    if (isneg) Eneg_s[off + rank] = E;
    const unsigned int L = (nneg + 31u) & ~31u;   // <= 256
    if ((unsigned int)j >= nneg && (unsigned int)j < L) Eneg_s[j] = 0.0f;  // pad: log(E+0)=p, corrected below
    __syncthreads();

    // ---- pairwise term: S = sum_k log(E + Eneg[k]) via grouped products ----
    // log1p(exp(p_n - p_p)) = log(E_p + E_n) - p_p ; zero-pad contributes exactly p_p each.
    float S = 0.0f;
    const float Ep = E;
    for (unsigned int k0 = 0; k0 < L; k0 += 32) {
        float pr0 = 1.0f, pr1 = 1.0f, pr2 = 1.0f, pr3 = 1.0f;
        #pragma unroll
        for (int kk = 0; kk < 32; kk += 4) {
            const float4 e = *reinterpret_cast<const float4*>(&Eneg_s[k0 + kk]);
            pr0 *= (Ep + e.x);
            pr1 *= (Ep + e.y);
            pr2 *= (Ep + e.z);
            pr3 *= (Ep + e.w);
        }
        S += __logf((pr0 * pr1) * (pr2 * pr3));   // product <= 5.34^32 ~ 2^77, fp32-safe
    }
    float pair = t * (S - p * (float)L);          // t in {0,1} masks non-positive rows

    // ---- block reduction of bce & pair ----
    float b = bce;
    #pragma unroll
    for (int o = 32; o > 0; o >>= 1) {
        b    += __shfl_down(b, o);
        pair += __shfl_down(pair, o);
    }
    if (lane == 0) { r0[wave] = b; r1[wave] = pair; }
    __syncthreads();

    if (j == 0) {
        const float bs = r0[0] + r0[1] + r0[2] + r0[3];
        const float ps = r1[0] + r1[1] + r1[2] + r1[3];
        const unsigned int npos = (unsigned int)C_DIM - nneg;
        // npos*nneg <= 128*128 = 16384: exact in f32
        part[row] = make_float4(bs, ps, (float)(npos * nneg), 0.0f);
    }
}

__global__ __launch_bounds__(256) void spa_lpr_final(const float4* __restrict__ part,
                                                     float* __restrict__ out) {
    __shared__ float rb[4], rp[4];
    __shared__ unsigned int rc[4];

    const int j    = threadIdx.x;
    const int lane = j & 63;
    const int wave = j >> 6;

    float b = 0.0f, p = 0.0f;
    unsigned int c = 0;
    #pragma unroll
    for (int k = 0; k < 4; ++k) {
        const float4 v = part[j + k * 256];
        b += v.x;
        p += v.y;
        c += (unsigned int)v.z;          // exact: v.z integer-valued <= 16384
    }
    #pragma unroll
    for (int o = 32; o > 0; o >>= 1) {
        b += __shfl_down(b, o);
        p += __shfl_down(p, o);
        c += __shfl_down(c, o);
    }
    if (lane == 0) { rb[wave] = b; rp[wave] = p; rc[wave] = c; }
    __syncthreads();
    if (j == 0) {
        const float bs = rb[0] + rb[1] + rb[2] + rb[3];
        const float ps = rp[0] + rp[1] + rp[2] + rp[3];
        const unsigned int cs = rc[0] + rc[1] + rc[2] + rc[3];
        out[0] = bs / (float)(B_DIM * C_DIM) + LAMBDA_LPR * (ps / ((float)cs + EPS));
    }
}

extern "C" void kernel_launch(void* const* d_in, const int* in_sizes, int n_in,
                              void* d_out, int out_size, void* d_ws, size_t ws_size,
                              hipStream_t stream) {
    const float* logits  = (const float*)d_in[0];
    const float* targets = (const float*)d_in[1];
    float* out = (float*)d_out;
    float4* part = (float4*)d_ws;        // 1024 * 16 B = 16 KB scratch

    spa_lpr_partial<<<B_DIM, 256, 0, stream>>>(logits, targets, part);
    spa_lpr_final<<<1, 256, 0, stream>>>(part, out);
}